// Round 1
// baseline (3011.308 us; speedup 1.0000x reference)
//
#include <hip/hip_runtime.h>

#define SEQ   8192
#define VOCAB 128000
#define L     64
#define NCH   128   // SEQ / L

// ws layout (float offsets)
#define OFF_CVEC 0        // cvecT[k][m][i]  : [64][128][10]
#define OFF_CW   81920    // Cw[t][j]        : [8192][10]  (embedding part of combined)
#define OFF_CH   163840   // Ch[k][i][m]     : [64][10][128] (hidden part, scan-friendly layout)
#define OFF_WT   245760   // WT[k][v]        : [20][128000] (transposed W_i2o)
// total = 2,805,760 floats = 11.2 MB

// ---------------------------------------------------------------------------
// K1: gather embeddings, write Cw, and compute cvec_t = W_i2h[:,:10]*w_t + b_i2h
// ---------------------------------------------------------------------------
__global__ void k_embed(const int* __restrict__ ix, const float* __restrict__ emb,
                        const float* __restrict__ Wih, const float* __restrict__ bih,
                        float* __restrict__ ws) {
    int t = blockIdx.x * blockDim.x + threadIdx.x;
    if (t >= SEQ) return;
    int id = ix[t];
    float w[10];
    const float2* ep = (const float2*)(emb + (long long)id * 10);
#pragma unroll
    for (int j = 0; j < 5; j++) ((float2*)w)[j] = ep[j];

    float* cw = ws + OFF_CW + t * 10;
#pragma unroll
    for (int j = 0; j < 10; j++) cw[j] = w[j];

    int m = t >> 6, k = t & 63;
    float* cv = ws + OFF_CVEC + (k * NCH + m) * 10;
#pragma unroll
    for (int i = 0; i < 10; i++) {
        float s = bih[i];
#pragma unroll
        for (int j = 0; j < 10; j++) s += Wih[i * 20 + j] * w[j];
        cv[i] = s;
    }
}

// ---------------------------------------------------------------------------
// K2: transpose W_i2o (VOCAB x 20, row-major) -> WT (20 x VOCAB)
// ---------------------------------------------------------------------------
__global__ void k_transpose(const float* __restrict__ Wio, float* __restrict__ ws) {
    int v = blockIdx.x * blockDim.x + threadIdx.x;
    if (v >= VOCAB) return;
    const float4* r = (const float4*)(Wio + (long long)v * 20);
    float vals[20];
#pragma unroll
    for (int q = 0; q < 5; q++) ((float4*)vals)[q] = r[q];
    float* WT = ws + OFF_WT;
#pragma unroll
    for (int k = 0; k < 20; k++) WT[k * VOCAB + v] = vals[k];
}

// ---------------------------------------------------------------------------
// K3: blocked scan of h_{t+1} = A h_t + c_t  (A = W_i2h[:,10:20], constant)
// one block of 128 threads: phase A (per-chunk from zero), phase B (A^64 +
// chunk-boundary scan), phase C (re-run chunks with true starts, write Ch)
// ---------------------------------------------------------------------------
__global__ void k_scan(const float* __restrict__ Wih, float* __restrict__ ws) {
    __shared__ float P[100], Q[100];
    __shared__ float Dl[NCH][10];
    __shared__ float Hst[NCH][10];
    __shared__ float Hl[10];
    int tid = threadIdx.x;

    // A in registers (constant-indexed, fully unrolled)
    float Ar[10][10];
#pragma unroll
    for (int i = 0; i < 10; i++)
#pragma unroll
        for (int j = 0; j < 10; j++) Ar[i][j] = Wih[i * 20 + 10 + j];

    // ---- phase A: each thread = one chunk, run from zero state ----
    {
        int m = tid;
        float h[10];
#pragma unroll
        for (int i = 0; i < 10; i++) h[i] = 0.f;
        const float* cvb = ws + OFF_CVEC;
        for (int k = 0; k < L; k++) {
            const float* c = cvb + (k * NCH + m) * 10;
            float nh[10];
#pragma unroll
            for (int i = 0; i < 10; i++) {
                float s = c[i];
#pragma unroll
                for (int j = 0; j < 10; j++) s += Ar[i][j] * h[j];
                nh[i] = s;
            }
#pragma unroll
            for (int i = 0; i < 10; i++) h[i] = nh[i];
        }
#pragma unroll
        for (int i = 0; i < 10; i++) Dl[m][i] = h[i];
    }

    // ---- phase B1: A^64 via 6 squarings in LDS ----
    if (tid < 100) P[tid] = Wih[(tid / 10) * 20 + 10 + (tid % 10)];
    __syncthreads();
    for (int it = 0; it < 6; it++) {
        if (tid < 100) {
            int i = tid / 10, j = tid % 10;
            float s = 0.f;
#pragma unroll
            for (int k = 0; k < 10; k++) s += P[i * 10 + k] * P[k * 10 + j];
            Q[tid] = s;
        }
        __syncthreads();
        if (tid < 100) P[tid] = Q[tid];
        __syncthreads();
    }

    // ---- phase B2: sequential chunk-boundary scan, lanes 0..9 of wave 0 ----
    if (tid < 10) Hl[tid] = 0.f;
    __syncthreads();
    if (tid < 10) {
        int i = tid;
        float a64[10];
#pragma unroll
        for (int j = 0; j < 10; j++) a64[j] = P[i * 10 + j];
        float hc = 0.f;
        for (int m = 0; m < NCH; m++) {
            Hst[m][i] = hc;           // chunk-start hidden H_m
            float s = Dl[m][i];
#pragma unroll
            for (int j = 0; j < 10; j++) s += a64[j] * Hl[j];  // reads before write (wave lockstep)
            Hl[i] = s;
            hc = s;
        }
    }
    __syncthreads();

    // ---- phase C: re-run chunks with true start hidden, write Ch[k][i][m] ----
    {
        int m = tid;
        float h[10];
#pragma unroll
        for (int i = 0; i < 10; i++) h[i] = Hst[m][i];
        const float* cvb = ws + OFF_CVEC;
        float* chb = ws + OFF_CH;
        for (int k = 0; k < L; k++) {
            float* chp = chb + k * 10 * NCH + m;
#pragma unroll
            for (int i = 0; i < 10; i++) chp[i * NCH] = h[i];  // h_t (pre-update) -> combined
            const float* c = cvb + (k * NCH + m) * 10;
            float nh[10];
#pragma unroll
            for (int i = 0; i < 10; i++) {
                float s = c[i];
#pragma unroll
                for (int j = 0; j < 10; j++) s += Ar[i][j] * h[j];
                nh[i] = s;
            }
#pragma unroll
            for (int i = 0; i < 10; i++) h[i] = nh[i];
        }
    }
}

// ---------------------------------------------------------------------------
// K4: fused logits + argmax. 512 blocks x 256 threads. Block owns 16 t's,
// scans all 128000 v (4 consecutive v per thread per iteration, 125 iters).
// ---------------------------------------------------------------------------
__global__ __launch_bounds__(256, 2)
void k_logits(const float* __restrict__ ws, const float* __restrict__ bio,
              float* __restrict__ out) {
    __shared__ float c_lds[20][16];
    __shared__ float wv[16][4];
    __shared__ int   wi[16][4];
    int tid = threadIdx.x;
    int t0 = blockIdx.x * 16;

    // stage combined[t0..t0+15][0..19] into LDS (k-major)
    for (int i = tid; i < 320; i += 256) {
        int t = i / 20, k = i % 20;
        int tg = t0 + t;
        float val;
        if (k < 10) val = ws[OFF_CW + tg * 10 + k];
        else {
            int m = tg >> 6, kk = tg & 63;
            val = ws[OFF_CH + (kk * 10 + (k - 10)) * NCH + m];
        }
        c_lds[k][t] = val;
    }
    __syncthreads();

    float best[16];
    int   bidx[16];
#pragma unroll
    for (int t = 0; t < 16; t++) { best[t] = -1e30f; bidx[t] = 0; }

    const float4* WT4 = (const float4*)(ws + OFF_WT);
    const float4* B4  = (const float4*)bio;

    for (int it = 0; it < 125; it++) {
        int vb = it * 256 + tid;      // float4 index; v0 = vb*4
        float4 b4 = B4[vb];
        float acc[16][4];
#pragma unroll
        for (int t = 0; t < 16; t++) {
            acc[t][0] = b4.x; acc[t][1] = b4.y; acc[t][2] = b4.z; acc[t][3] = b4.w;
        }
#pragma unroll
        for (int k = 0; k < 20; k++) {
            float4 w4 = WT4[k * 32000 + vb];
            const float4* cp = (const float4*)(&c_lds[k][0]);
            float4 c0 = cp[0], c1 = cp[1], c2 = cp[2], c3 = cp[3];
            float cvv[16];
            ((float4*)cvv)[0] = c0; ((float4*)cvv)[1] = c1;
            ((float4*)cvv)[2] = c2; ((float4*)cvv)[3] = c3;
#pragma unroll
            for (int t = 0; t < 16; t++) {
                acc[t][0] += cvv[t] * w4.x;
                acc[t][1] += cvv[t] * w4.y;
                acc[t][2] += cvv[t] * w4.z;
                acc[t][3] += cvv[t] * w4.w;
            }
        }
        int v0 = vb * 4;
#pragma unroll
        for (int t = 0; t < 16; t++) {
#pragma unroll
            for (int j = 0; j < 4; j++) {
                if (acc[t][j] > best[t]) { best[t] = acc[t][j]; bidx[t] = v0 + j; }
            }
        }
    }

    // reduce across 256 threads (ascending-v order preserved; ties -> lower idx)
    int lane = tid & 63, wave = tid >> 6;
#pragma unroll
    for (int t = 0; t < 16; t++) {
        float bv = best[t]; int bi = bidx[t];
        for (int off = 32; off > 0; off >>= 1) {
            float ov = __shfl_down(bv, off);
            int   oi = __shfl_down(bi, off);
            if (ov > bv || (ov == bv && oi < bi)) { bv = ov; bi = oi; }
        }
        if (lane == 0) { wv[t][wave] = bv; wi[t][wave] = bi; }
    }
    __syncthreads();
    if (tid < 16) {
        float bv = wv[tid][0]; int bi = wi[tid][0];
        for (int w = 1; w < 4; w++) {
            float ov = wv[tid][w]; int oi = wi[tid][w];
            if (ov > bv || (ov == bv && oi < bi)) { bv = ov; bi = oi; }
        }
        out[t0 + tid] = (float)bi;
    }
}

// ---------------------------------------------------------------------------
extern "C" void kernel_launch(void* const* d_in, const int* in_sizes, int n_in,
                              void* d_out, int out_size, void* d_ws, size_t ws_size,
                              hipStream_t stream) {
    (void)in_sizes; (void)n_in; (void)out_size; (void)ws_size;
    const int*   ix  = (const int*)d_in[0];
    const float* emb = (const float*)d_in[1];
    const float* Wih = (const float*)d_in[2];
    const float* bih = (const float*)d_in[3];
    const float* Wio = (const float*)d_in[4];
    const float* bio = (const float*)d_in[5];
    float* out = (float*)d_out;
    float* ws  = (float*)d_ws;

    hipLaunchKernelGGL(k_embed,     dim3(SEQ / 256), dim3(256), 0, stream, ix, emb, Wih, bih, ws);
    hipLaunchKernelGGL(k_transpose, dim3(VOCAB / 256), dim3(256), 0, stream, Wio, ws);
    hipLaunchKernelGGL(k_scan,      dim3(1), dim3(128), 0, stream, Wih, ws);
    hipLaunchKernelGGL(k_logits,    dim3(SEQ / 16), dim3(256), 0, stream, ws, bio, out);
}